// Round 4
// baseline (133.347 us; speedup 1.0000x reference)
//
#include <hip/hip_runtime.h>

// Problem constants (B=8, V=8192, N=2048, C=128)
#define BB 8
#define VV 8192
#define NN 2048
#define CC 128

#define SELT_LD 68   // padded leading dim for transposed sel tile

// ---------------------------------------------------------------------------
// Kernel A: mlp_out[row] = relu(processed[row,:] @ W1 + b1) @ W2 + b2
// rows = B*N = 16384 (4x less work than B*V since output depends only on
// processed[b, idx] and idx has range N). 64 rows/block, 256 threads.
// ---------------------------------------------------------------------------
__global__ __launch_bounds__(256) void mlp_rows_kernel(
    const float* __restrict__ processed, const float* __restrict__ W1,
    const float* __restrict__ b1, const float* __restrict__ W2,
    const float* __restrict__ b2, float* __restrict__ mlp_out)
{
    __shared__ float selT[CC * SELT_LD]; // selT[k][r], r in [0,64)
    const int t = threadIdx.x;
    const int row0 = blockIdx.x * 64;

    #pragma unroll
    for (int i = 0; i < 32; ++i) {
        int flat = i * 256 + t;        // 0..8191
        int r = flat >> 7;             // 0..63
        int k = flat & 127;
        selT[k * SELT_LD + r] = processed[(size_t)(row0 + r) * CC + k];
    }
    __syncthreads();

    const int g = t & 31;        // 0..31 -> 4 cols each
    const int rblk = t >> 5;     // 0..7  -> 8 rows each
    const int c0 = g * 4;
    const int r0 = rblk * 8;

    float acc[8][4];
    #pragma unroll
    for (int i = 0; i < 8; ++i)
        #pragma unroll
        for (int j = 0; j < 4; ++j) acc[i][j] = 0.f;

    #pragma unroll 4
    for (int k = 0; k < CC; ++k) {
        float4 bv = *(const float4*)(W1 + k * CC + c0);
        const float* sp = &selT[k * SELT_LD + r0];
        float4 a0 = *(const float4*)(sp);
        float4 a1 = *(const float4*)(sp + 4);
        float av[8] = {a0.x, a0.y, a0.z, a0.w, a1.x, a1.y, a1.z, a1.w};
        #pragma unroll
        for (int i = 0; i < 8; ++i) {
            acc[i][0] = fmaf(av[i], bv.x, acc[i][0]);
            acc[i][1] = fmaf(av[i], bv.y, acc[i][1]);
            acc[i][2] = fmaf(av[i], bv.z, acc[i][2]);
            acc[i][3] = fmaf(av[i], bv.w, acc[i][3]);
        }
    }

    float4 b1v = *(const float4*)(b1 + c0);
    float4 w2v = *(const float4*)(W2 + c0);
    float bias2 = b2[0];

    #pragma unroll
    for (int i = 0; i < 8; ++i) {
        float h0 = acc[i][0] + b1v.x; h0 = h0 > 0.f ? h0 : 0.f;
        float h1 = acc[i][1] + b1v.y; h1 = h1 > 0.f ? h1 : 0.f;
        float h2 = acc[i][2] + b1v.z; h2 = h2 > 0.f ? h2 : 0.f;
        float h3 = acc[i][3] + b1v.w; h3 = h3 > 0.f ? h3 : 0.f;
        float p = fmaf(h0, w2v.x, fmaf(h1, w2v.y, fmaf(h2, w2v.z, h3 * w2v.w)));
        #pragma unroll
        for (int off = 1; off < 32; off <<= 1) p += __shfl_xor(p, off, 64);
        if (g == 0) mlp_out[row0 + r0 + i] = p + bias2;
    }
}

// ---------------------------------------------------------------------------
// Kernel B: per-vertex argmin over N graph points + gather of mlp_out.
// d2 replicates the expanded form; the -2*v.p inner product uses an FMA
// CHAIN (BLAS sgemm / Eigen / XLA-CPU dot_general contraction order):
//   e  = fma(vz,pz, fma(vy,py, rn(vx*px)))
// while the elementwise/reduce parts keep sequential f32 rounding:
//   sv = (rn(vx^2)+rn(vy^2))+rn(vz^2) ; sp likewise
//   d2 = (sv - 2*e) + sp                (2*e exact)
// Goal: bit-match the np/jax reference's GEMM-path arithmetic so near-tie
// argmin picks agree. Strict < keeps first index on exact ties.
// Block = 256 thr = 64 vertices x 4 point-chunks of 512.
// ---------------------------------------------------------------------------
__global__ __launch_bounds__(256) void argmin_gather_kernel(
    const float* __restrict__ verts, const float* __restrict__ graph_pos,
    const float* __restrict__ mlp_out, float* __restrict__ out)
{
    const int bid = blockIdx.x;
    const int b = bid >> 7;                 // / (V/64)
    const int v0 = (bid & 127) * 64;
    const int t = threadIdx.x;
    const int lane = t & 63;
    const int chunk = __builtin_amdgcn_readfirstlane(t >> 6); // wave-uniform 0..3

    const int v = v0 + lane;
    const float* vp = verts + ((size_t)b * VV + v) * 3;
    const float vx = vp[0], vy = vp[1], vz = vp[2];
    const float sv = __fadd_rn(__fadd_rn(__fmul_rn(vx, vx), __fmul_rn(vy, vy)),
                               __fmul_rn(vz, vz));

    const float* gp = graph_pos + ((size_t)b * NN + (size_t)chunk * 512) * 3;

    float best = 3.4e38f;
    int bi = 0;
    #pragma unroll 8
    for (int n = 0; n < 512; ++n) {
        float px = gp[3 * n + 0];
        float py = gp[3 * n + 1];
        float pz = gp[3 * n + 2];
        float sp = __fadd_rn(__fadd_rn(__fmul_rn(px, px), __fmul_rn(py, py)),
                             __fmul_rn(pz, pz));
        float e  = fmaf(vz, pz, fmaf(vy, py, __fmul_rn(vx, px)));  // fma chain
        float d2 = __fadd_rn(__fsub_rn(sv, __fmul_rn(2.0f, e)), sp);
        if (d2 < best) { best = d2; bi = n; }   // strict < keeps first index
    }
    bi += chunk * 512;

    __shared__ float sd[256];
    __shared__ int   si[256];
    sd[t] = best;
    si[t] = bi;
    __syncthreads();

    if (t < 64) {
        // ascending chunk order + strict < preserves smallest-index tie-break
        #pragma unroll
        for (int c = 1; c < 4; ++c) {
            float d = sd[c * 64 + lane];
            int   i = si[c * 64 + lane];
            if (d < best) { best = d; bi = i; }
        }
        out[(size_t)b * VV + v] = mlp_out[b * NN + bi];
    }
}

extern "C" void kernel_launch(void* const* d_in, const int* in_sizes, int n_in,
                              void* d_out, int out_size, void* d_ws, size_t ws_size,
                              hipStream_t stream) {
    const float* verts     = (const float*)d_in[0];
    const float* graph_pos = (const float*)d_in[1];
    const float* processed = (const float*)d_in[2];
    const float* W1        = (const float*)d_in[3];
    const float* b1        = (const float*)d_in[4];
    const float* W2        = (const float*)d_in[5];
    const float* b2        = (const float*)d_in[6];
    float* out     = (float*)d_out;
    float* mlp_out = (float*)d_ws;     // 16384 floats = 64 KB scratch

    hipLaunchKernelGGL(mlp_rows_kernel, dim3((BB * NN) / 64), dim3(256), 0, stream,
                       processed, W1, b1, W2, b2, mlp_out);
    hipLaunchKernelGGL(argmin_gather_kernel, dim3(BB * (VV / 64)), dim3(256), 0, stream,
                       verts, graph_pos, mlp_out, out);
}

// Round 5
// 129.717 us; speedup vs baseline: 1.0280x; 1.0280x over previous
//
#include <hip/hip_runtime.h>

// Problem constants (B=8, V=8192, N=2048, C=128)
#define BB 8
#define VV 8192
#define NN 2048
#define CC 128

// ===========================================================================
// FAST PATH
// ===========================================================================

#define MLP_LD 36     // 128 x 36 f32 selT tile: 16B-aligned rows, conflict-free b128 reads

// Kernel 1: blocks [0,512): MLP over B*N rows (32 rows/block, 4x4 micro-tile)
//           blocks [512,528): qpt precompute {px,py,pz,sp} per (b,n)
// sp uses the EXACT reference rounding: (rn(px^2)+rn(py^2))+rn(pz^2).
__global__ __launch_bounds__(256) void mlp_qpt_kernel(
    const float* __restrict__ processed, const float* __restrict__ W1,
    const float* __restrict__ b1, const float* __restrict__ W2,
    const float* __restrict__ b2, const float* __restrict__ graph_pos,
    float* __restrict__ mlp_out, float4* __restrict__ qpt)
{
    const int t = threadIdx.x;

    if (blockIdx.x >= 512) {
        // ---- qpt part: 16 blocks x 256 thr x 4 points (stride-coalesced) ----
        const int base = (blockIdx.x - 512) * 256 + t;   // 0..4095
        #pragma unroll
        for (int i = 0; i < 4; ++i) {
            int p = base + i * 4096;                     // 0..16383 = b*NN+n
            const float* g3 = graph_pos + 3 * (size_t)p;
            float px = g3[0], py = g3[1], pz = g3[2];
            float sp = __fadd_rn(__fadd_rn(__fmul_rn(px, px), __fmul_rn(py, py)),
                                 __fmul_rn(pz, pz));
            qpt[p] = make_float4(px, py, pz, sp);
        }
        return;
    }

    // ---- MLP part: 32 rows per block ----
    __shared__ float selT[CC * MLP_LD];   // selT[k][r], r in [0,32)
    const int row0 = blockIdx.x * 32;

    #pragma unroll
    for (int i = 0; i < 16; ++i) {
        int flat = i * 256 + t;           // 0..4095
        int r = flat >> 7;                // 0..31
        int k = flat & 127;
        selT[k * MLP_LD + r] = processed[(size_t)(row0 + r) * CC + k];
    }
    __syncthreads();

    const int g = t & 31;                 // col group: 4 cols each
    const int rblk = t >> 5;              // row group: 4 rows each (8 groups x 4 = 32)
    const int c0 = g * 4;
    const int r0 = rblk * 4;

    float acc[4][4];
    #pragma unroll
    for (int i = 0; i < 4; ++i)
        #pragma unroll
        for (int j = 0; j < 4; ++j) acc[i][j] = 0.f;

    #pragma unroll 4
    for (int k = 0; k < CC; ++k) {
        float4 wv = *(const float4*)(W1 + k * CC + c0);
        float4 av4 = *(const float4*)(&selT[k * MLP_LD + r0]);
        float av[4] = {av4.x, av4.y, av4.z, av4.w};
        #pragma unroll
        for (int i = 0; i < 4; ++i) {
            acc[i][0] = fmaf(av[i], wv.x, acc[i][0]);
            acc[i][1] = fmaf(av[i], wv.y, acc[i][1]);
            acc[i][2] = fmaf(av[i], wv.z, acc[i][2]);
            acc[i][3] = fmaf(av[i], wv.w, acc[i][3]);
        }
    }

    float4 b1v = *(const float4*)(b1 + c0);
    float4 w2v = *(const float4*)(W2 + c0);
    float bias2 = b2[0];

    #pragma unroll
    for (int i = 0; i < 4; ++i) {
        float h0 = acc[i][0] + b1v.x; h0 = h0 > 0.f ? h0 : 0.f;
        float h1 = acc[i][1] + b1v.y; h1 = h1 > 0.f ? h1 : 0.f;
        float h2 = acc[i][2] + b1v.z; h2 = h2 > 0.f ? h2 : 0.f;
        float h3 = acc[i][3] + b1v.w; h3 = h3 > 0.f ? h3 : 0.f;
        float p = fmaf(h0, w2v.x, fmaf(h1, w2v.y, fmaf(h2, w2v.z, h3 * w2v.w)));
        // reduce across the 32 col-lanes (xor offsets <32 stay in each half-wave)
        #pragma unroll
        for (int off = 1; off < 32; off <<= 1) p += __shfl_xor(p, off, 64);
        if (g == 0) mlp_out[row0 + r0 + i] = p + bias2;
    }
}

// Kernel 2: argmin + gather. 8-VALU-op inner body:
//   e2 = fma(2vz,pz, fma(2vy,py, rn(2vx*px)))   == rn(2e) bitwise (x2 exact)
//   d2 = rn(rn(sv - e2) + sp)                    identical to reference
// qpt fetch is wave-uniform (chunk readfirstlane'd) -> s_load path.
__global__ __launch_bounds__(256) void argmin_gather_fast_kernel(
    const float* __restrict__ verts, const float4* __restrict__ qpt,
    const float* __restrict__ mlp_out, float* __restrict__ out)
{
    const int bid = blockIdx.x;
    const int b = bid >> 7;                 // / (V/64)
    const int v0 = (bid & 127) * 64;
    const int t = threadIdx.x;
    const int lane = t & 63;
    const int chunk = __builtin_amdgcn_readfirstlane(t >> 6); // 0..3

    const int v = v0 + lane;
    const float* vp = verts + ((size_t)b * VV + v) * 3;
    const float vx = vp[0], vy = vp[1], vz = vp[2];
    const float sv = __fadd_rn(__fadd_rn(__fmul_rn(vx, vx), __fmul_rn(vy, vy)),
                               __fmul_rn(vz, vz));
    const float tx = vx + vx, ty = vy + vy, tz = vz + vz;   // exact 2x

    const float4* q = qpt + (size_t)b * NN + (size_t)chunk * 512;

    float best = 3.4e38f;
    int bi = 0;
    #pragma unroll 8
    for (int n = 0; n < 512; ++n) {
        float4 Q = q[n];
        float e2 = fmaf(tz, Q.z, fmaf(ty, Q.y, __fmul_rn(tx, Q.x)));
        float d2 = __fadd_rn(__fsub_rn(sv, e2), Q.w);
        if (d2 < best) { best = d2; bi = n; }   // strict < keeps first index
    }
    bi += chunk * 512;

    __shared__ float sd[256];
    __shared__ int   si[256];
    sd[t] = best;
    si[t] = bi;
    __syncthreads();

    if (t < 64) {
        #pragma unroll
        for (int c = 1; c < 4; ++c) {           // ascending chunks: first-index ties
            float d = sd[c * 64 + lane];
            int   i = si[c * 64 + lane];
            if (d < best) { best = d; bi = i; }
        }
        out[(size_t)b * VV + v] = mlp_out[b * NN + bi];
    }
}

// ===========================================================================
// FALLBACK PATH (round-4 proven kernels; used only if ws_size is too small)
// ===========================================================================
#define SELT_LD 68

__global__ __launch_bounds__(256) void mlp_rows_kernel(
    const float* __restrict__ processed, const float* __restrict__ W1,
    const float* __restrict__ b1, const float* __restrict__ W2,
    const float* __restrict__ b2, float* __restrict__ mlp_out)
{
    __shared__ float selT[CC * SELT_LD];
    const int t = threadIdx.x;
    const int row0 = blockIdx.x * 64;
    #pragma unroll
    for (int i = 0; i < 32; ++i) {
        int flat = i * 256 + t;
        int r = flat >> 7;
        int k = flat & 127;
        selT[k * SELT_LD + r] = processed[(size_t)(row0 + r) * CC + k];
    }
    __syncthreads();
    const int g = t & 31, rblk = t >> 5;
    const int c0 = g * 4, r0 = rblk * 8;
    float acc[8][4];
    #pragma unroll
    for (int i = 0; i < 8; ++i)
        #pragma unroll
        for (int j = 0; j < 4; ++j) acc[i][j] = 0.f;
    #pragma unroll 4
    for (int k = 0; k < CC; ++k) {
        float4 bv = *(const float4*)(W1 + k * CC + c0);
        const float* sp = &selT[k * SELT_LD + r0];
        float4 a0 = *(const float4*)(sp);
        float4 a1 = *(const float4*)(sp + 4);
        float av[8] = {a0.x, a0.y, a0.z, a0.w, a1.x, a1.y, a1.z, a1.w};
        #pragma unroll
        for (int i = 0; i < 8; ++i) {
            acc[i][0] = fmaf(av[i], bv.x, acc[i][0]);
            acc[i][1] = fmaf(av[i], bv.y, acc[i][1]);
            acc[i][2] = fmaf(av[i], bv.z, acc[i][2]);
            acc[i][3] = fmaf(av[i], bv.w, acc[i][3]);
        }
    }
    float4 b1v = *(const float4*)(b1 + c0);
    float4 w2v = *(const float4*)(W2 + c0);
    float bias2 = b2[0];
    #pragma unroll
    for (int i = 0; i < 8; ++i) {
        float h0 = acc[i][0] + b1v.x; h0 = h0 > 0.f ? h0 : 0.f;
        float h1 = acc[i][1] + b1v.y; h1 = h1 > 0.f ? h1 : 0.f;
        float h2 = acc[i][2] + b1v.z; h2 = h2 > 0.f ? h2 : 0.f;
        float h3 = acc[i][3] + b1v.w; h3 = h3 > 0.f ? h3 : 0.f;
        float p = fmaf(h0, w2v.x, fmaf(h1, w2v.y, fmaf(h2, w2v.z, h3 * w2v.w)));
        #pragma unroll
        for (int off = 1; off < 32; off <<= 1) p += __shfl_xor(p, off, 64);
        if (g == 0) mlp_out[row0 + r0 + i] = p + bias2;
    }
}

__global__ __launch_bounds__(256) void argmin_gather_kernel(
    const float* __restrict__ verts, const float* __restrict__ graph_pos,
    const float* __restrict__ mlp_out, float* __restrict__ out)
{
    const int bid = blockIdx.x;
    const int b = bid >> 7;
    const int v0 = (bid & 127) * 64;
    const int t = threadIdx.x;
    const int lane = t & 63;
    const int chunk = __builtin_amdgcn_readfirstlane(t >> 6);
    const int v = v0 + lane;
    const float* vp = verts + ((size_t)b * VV + v) * 3;
    const float vx = vp[0], vy = vp[1], vz = vp[2];
    const float sv = __fadd_rn(__fadd_rn(__fmul_rn(vx, vx), __fmul_rn(vy, vy)),
                               __fmul_rn(vz, vz));
    const float* gp = graph_pos + ((size_t)b * NN + (size_t)chunk * 512) * 3;
    float best = 3.4e38f;
    int bi = 0;
    #pragma unroll 8
    for (int n = 0; n < 512; ++n) {
        float px = gp[3 * n + 0], py = gp[3 * n + 1], pz = gp[3 * n + 2];
        float sp = __fadd_rn(__fadd_rn(__fmul_rn(px, px), __fmul_rn(py, py)),
                             __fmul_rn(pz, pz));
        float e  = fmaf(vz, pz, fmaf(vy, py, __fmul_rn(vx, px)));
        float d2 = __fadd_rn(__fsub_rn(sv, __fmul_rn(2.0f, e)), sp);
        if (d2 < best) { best = d2; bi = n; }
    }
    bi += chunk * 512;
    __shared__ float sd[256];
    __shared__ int   si[256];
    sd[t] = best;
    si[t] = bi;
    __syncthreads();
    if (t < 64) {
        #pragma unroll
        for (int c = 1; c < 4; ++c) {
            float d = sd[c * 64 + lane];
            int   i = si[c * 64 + lane];
            if (d < best) { best = d; bi = i; }
        }
        out[(size_t)b * VV + v] = mlp_out[b * NN + bi];
    }
}

extern "C" void kernel_launch(void* const* d_in, const int* in_sizes, int n_in,
                              void* d_out, int out_size, void* d_ws, size_t ws_size,
                              hipStream_t stream) {
    const float* verts     = (const float*)d_in[0];
    const float* graph_pos = (const float*)d_in[1];
    const float* processed = (const float*)d_in[2];
    const float* W1        = (const float*)d_in[3];
    const float* b1        = (const float*)d_in[4];
    const float* W2        = (const float*)d_in[5];
    const float* b2        = (const float*)d_in[6];
    float* out     = (float*)d_out;
    float* mlp_out = (float*)d_ws;                               // 64 KB
    float4* qpt    = (float4*)((char*)d_ws + BB * NN * 4);       // 256 KB

    const size_t need = (size_t)BB * NN * 4 + (size_t)BB * NN * 16;
    if (ws_size >= need) {
        hipLaunchKernelGGL(mlp_qpt_kernel, dim3(528), dim3(256), 0, stream,
                           processed, W1, b1, W2, b2, graph_pos, mlp_out, qpt);
        hipLaunchKernelGGL(argmin_gather_fast_kernel, dim3(BB * (VV / 64)), dim3(256), 0, stream,
                           verts, qpt, mlp_out, out);
    } else {
        hipLaunchKernelGGL(mlp_rows_kernel, dim3((BB * NN) / 64), dim3(256), 0, stream,
                           processed, W1, b1, W2, b2, mlp_out);
        hipLaunchKernelGGL(argmin_gather_kernel, dim3(BB * (VV / 64)), dim3(256), 0, stream,
                           verts, graph_pos, mlp_out, out);
    }
}

// Round 6
// 110.407 us; speedup vs baseline: 1.2078x; 1.1749x over previous
//
#include <hip/hip_runtime.h>

// Problem constants (B=8, V=8192, N=2048, C=128)
#define BB 8
#define VV 8192
#define NN 2048
#define CC 128

// ===========================================================================
// FAST PATH
// ===========================================================================

#define MLP_LD 36     // 128 x 36 f32 selT tile: 16B-aligned rows, conflict-free b128 reads

// Kernel 1: blocks [0,512): MLP over B*N rows (32 rows/block, 4x4 micro-tile)
//           blocks [512,528): qpt precompute {px,py,pz,sp} per (b,n)
// sp uses the EXACT reference rounding: (rn(px^2)+rn(py^2))+rn(pz^2).
__global__ __launch_bounds__(256) void mlp_qpt_kernel(
    const float* __restrict__ processed, const float* __restrict__ W1,
    const float* __restrict__ b1, const float* __restrict__ W2,
    const float* __restrict__ b2, const float* __restrict__ graph_pos,
    float* __restrict__ mlp_out, float4* __restrict__ qpt)
{
    const int t = threadIdx.x;

    if (blockIdx.x >= 512) {
        // ---- qpt part: 16 blocks x 256 thr x 4 points ----
        const int base = (blockIdx.x - 512) * 256 + t;   // 0..4095
        #pragma unroll
        for (int i = 0; i < 4; ++i) {
            int p = base + i * 4096;                     // 0..16383 = b*NN+n
            const float* g3 = graph_pos + 3 * (size_t)p;
            float px = g3[0], py = g3[1], pz = g3[2];
            float sp = __fadd_rn(__fadd_rn(__fmul_rn(px, px), __fmul_rn(py, py)),
                                 __fmul_rn(pz, pz));
            qpt[p] = make_float4(px, py, pz, sp);
        }
        return;
    }

    // ---- MLP part: 32 rows per block ----
    __shared__ float selT[CC * MLP_LD];   // selT[k][r], r in [0,32)
    const int row0 = blockIdx.x * 32;

    #pragma unroll
    for (int i = 0; i < 16; ++i) {
        int flat = i * 256 + t;           // 0..4095
        int r = flat >> 7;                // 0..31
        int k = flat & 127;
        selT[k * MLP_LD + r] = processed[(size_t)(row0 + r) * CC + k];
    }
    __syncthreads();

    const int g = t & 31;                 // col group: 4 cols each
    const int rblk = t >> 5;              // row group: 4 rows each
    const int c0 = g * 4;
    const int r0 = rblk * 4;

    float acc[4][4];
    #pragma unroll
    for (int i = 0; i < 4; ++i)
        #pragma unroll
        for (int j = 0; j < 4; ++j) acc[i][j] = 0.f;

    #pragma unroll 4
    for (int k = 0; k < CC; ++k) {
        float4 wv = *(const float4*)(W1 + k * CC + c0);
        float4 av4 = *(const float4*)(&selT[k * MLP_LD + r0]);
        float av[4] = {av4.x, av4.y, av4.z, av4.w};
        #pragma unroll
        for (int i = 0; i < 4; ++i) {
            acc[i][0] = fmaf(av[i], wv.x, acc[i][0]);
            acc[i][1] = fmaf(av[i], wv.y, acc[i][1]);
            acc[i][2] = fmaf(av[i], wv.z, acc[i][2]);
            acc[i][3] = fmaf(av[i], wv.w, acc[i][3]);
        }
    }

    float4 b1v = *(const float4*)(b1 + c0);
    float4 w2v = *(const float4*)(W2 + c0);
    float bias2 = b2[0];

    #pragma unroll
    for (int i = 0; i < 4; ++i) {
        float h0 = acc[i][0] + b1v.x; h0 = h0 > 0.f ? h0 : 0.f;
        float h1 = acc[i][1] + b1v.y; h1 = h1 > 0.f ? h1 : 0.f;
        float h2 = acc[i][2] + b1v.z; h2 = h2 > 0.f ? h2 : 0.f;
        float h3 = acc[i][3] + b1v.w; h3 = h3 > 0.f ? h3 : 0.f;
        float p = fmaf(h0, w2v.x, fmaf(h1, w2v.y, fmaf(h2, w2v.z, h3 * w2v.w)));
        #pragma unroll
        for (int off = 1; off < 32; off <<= 1) p += __shfl_xor(p, off, 64);
        if (g == 0) mlp_out[row0 + r0 + i] = p + bias2;
    }
}

// Kernel 2: argmin + gather, LDS-staged points.
// Block = 512 thr = 8 waves; block covers 128 vertices (Vt=2 per lane);
// wave w scans point chunk [w*256, (w+1)*256). All 2048 points staged in LDS;
// inner loop = ds_read_b128 broadcast (same-addr, conflict-free) + 16 VALU.
// Bit-exact d2: e2 = fma(2vz,pz, fma(2vy,py, rn(2vx*px))) == rn(2e);
//              d2 = rn(rn(sv - e2) + sp). Strict < + ascending chunk merge
//              preserves first-index tie-break.
__global__ __launch_bounds__(512) void argmin_gather_lds_kernel(
    const float* __restrict__ verts, const float4* __restrict__ qpt,
    const float* __restrict__ mlp_out, float* __restrict__ out)
{
    __shared__ float4 pts[NN];        // 32 KB
    __shared__ float  sd[8 * 128];    // 4 KB
    __shared__ int    si[8 * 128];    // 4 KB

    const int bid = blockIdx.x;       // 512 blocks
    const int b  = bid >> 6;          // 64 blocks per batch
    const int v0 = (bid & 63) * 128;
    const int t = threadIdx.x;
    const int lane = t & 63;
    const int w = __builtin_amdgcn_readfirstlane(t >> 6);   // wave id = chunk id, 0..7

    // stage all 2048 points of batch b (coalesced, 16B/lane)
    const float4* qb = qpt + (size_t)b * NN;
    #pragma unroll
    for (int i = 0; i < 4; ++i) pts[t + i * 512] = qb[t + i * 512];

    // two vertices per lane
    const int vA = v0 + lane;
    const int vB = v0 + 64 + lane;
    const float* vpA = verts + ((size_t)b * VV + vA) * 3;
    const float* vpB = verts + ((size_t)b * VV + vB) * 3;
    const float axv = vpA[0], ayv = vpA[1], azv = vpA[2];
    const float bxv = vpB[0], byv = vpB[1], bzv = vpB[2];
    const float svA = __fadd_rn(__fadd_rn(__fmul_rn(axv, axv), __fmul_rn(ayv, ayv)),
                                __fmul_rn(azv, azv));
    const float svB = __fadd_rn(__fadd_rn(__fmul_rn(bxv, bxv), __fmul_rn(byv, byv)),
                                __fmul_rn(bzv, bzv));
    const float txA = axv + axv, tyA = ayv + ayv, tzA = azv + azv;  // exact 2x
    const float txB = bxv + bxv, tyB = byv + byv, tzB = bzv + bzv;

    __syncthreads();

    const float4* P = &pts[w * 256];
    float bestA = 3.4e38f, bestB = 3.4e38f;
    int biA = 0, biB = 0;
    #pragma unroll 8
    for (int n = 0; n < 256; ++n) {
        float4 Q = P[n];   // ds_read_b128, broadcast
        float e2A = fmaf(tzA, Q.z, fmaf(tyA, Q.y, __fmul_rn(txA, Q.x)));
        float d2A = __fadd_rn(__fsub_rn(svA, e2A), Q.w);
        if (d2A < bestA) { bestA = d2A; biA = n; }
        float e2B = fmaf(tzB, Q.z, fmaf(tyB, Q.y, __fmul_rn(txB, Q.x)));
        float d2B = __fadd_rn(__fsub_rn(svB, e2B), Q.w);
        if (d2B < bestB) { bestB = d2B; biB = n; }
    }
    biA += w * 256;
    biB += w * 256;

    sd[w * 128 + lane]      = bestA;  si[w * 128 + lane]      = biA;
    sd[w * 128 + 64 + lane] = bestB;  si[w * 128 + 64 + lane] = biB;
    __syncthreads();

    if (t < 128) {
        float best = sd[t];
        int   bi   = si[t];
        #pragma unroll
        for (int c = 1; c < 8; ++c) {          // ascending chunks: first-index ties
            float d = sd[c * 128 + t];
            int   i = si[c * 128 + t];
            if (d < best) { best = d; bi = i; }
        }
        out[(size_t)b * VV + v0 + t] = mlp_out[b * NN + bi];
    }
}

// ===========================================================================
// FALLBACK PATH (round-4 proven kernels; used only if ws_size is too small)
// ===========================================================================
#define SELT_LD 68

__global__ __launch_bounds__(256) void mlp_rows_kernel(
    const float* __restrict__ processed, const float* __restrict__ W1,
    const float* __restrict__ b1, const float* __restrict__ W2,
    const float* __restrict__ b2, float* __restrict__ mlp_out)
{
    __shared__ float selT[CC * SELT_LD];
    const int t = threadIdx.x;
    const int row0 = blockIdx.x * 64;
    #pragma unroll
    for (int i = 0; i < 32; ++i) {
        int flat = i * 256 + t;
        int r = flat >> 7;
        int k = flat & 127;
        selT[k * SELT_LD + r] = processed[(size_t)(row0 + r) * CC + k];
    }
    __syncthreads();
    const int g = t & 31, rblk = t >> 5;
    const int c0 = g * 4, r0 = rblk * 8;
    float acc[8][4];
    #pragma unroll
    for (int i = 0; i < 8; ++i)
        #pragma unroll
        for (int j = 0; j < 4; ++j) acc[i][j] = 0.f;
    #pragma unroll 4
    for (int k = 0; k < CC; ++k) {
        float4 bv = *(const float4*)(W1 + k * CC + c0);
        const float* sp = &selT[k * SELT_LD + r0];
        float4 a0 = *(const float4*)(sp);
        float4 a1 = *(const float4*)(sp + 4);
        float av[8] = {a0.x, a0.y, a0.z, a0.w, a1.x, a1.y, a1.z, a1.w};
        #pragma unroll
        for (int i = 0; i < 8; ++i) {
            acc[i][0] = fmaf(av[i], bv.x, acc[i][0]);
            acc[i][1] = fmaf(av[i], bv.y, acc[i][1]);
            acc[i][2] = fmaf(av[i], bv.z, acc[i][2]);
            acc[i][3] = fmaf(av[i], bv.w, acc[i][3]);
        }
    }
    float4 b1v = *(const float4*)(b1 + c0);
    float4 w2v = *(const float4*)(W2 + c0);
    float bias2 = b2[0];
    #pragma unroll
    for (int i = 0; i < 8; ++i) {
        float h0 = acc[i][0] + b1v.x; h0 = h0 > 0.f ? h0 : 0.f;
        float h1 = acc[i][1] + b1v.y; h1 = h1 > 0.f ? h1 : 0.f;
        float h2 = acc[i][2] + b1v.z; h2 = h2 > 0.f ? h2 : 0.f;
        float h3 = acc[i][3] + b1v.w; h3 = h3 > 0.f ? h3 : 0.f;
        float p = fmaf(h0, w2v.x, fmaf(h1, w2v.y, fmaf(h2, w2v.z, h3 * w2v.w)));
        #pragma unroll
        for (int off = 1; off < 32; off <<= 1) p += __shfl_xor(p, off, 64);
        if (g == 0) mlp_out[row0 + r0 + i] = p + bias2;
    }
}

__global__ __launch_bounds__(256) void argmin_gather_kernel(
    const float* __restrict__ verts, const float* __restrict__ graph_pos,
    const float* __restrict__ mlp_out, float* __restrict__ out)
{
    const int bid = blockIdx.x;
    const int b = bid >> 7;
    const int v0 = (bid & 127) * 64;
    const int t = threadIdx.x;
    const int lane = t & 63;
    const int chunk = __builtin_amdgcn_readfirstlane(t >> 6);
    const int v = v0 + lane;
    const float* vp = verts + ((size_t)b * VV + v) * 3;
    const float vx = vp[0], vy = vp[1], vz = vp[2];
    const float sv = __fadd_rn(__fadd_rn(__fmul_rn(vx, vx), __fmul_rn(vy, vy)),
                               __fmul_rn(vz, vz));
    const float* gp = graph_pos + ((size_t)b * NN + (size_t)chunk * 512) * 3;
    float best = 3.4e38f;
    int bi = 0;
    #pragma unroll 8
    for (int n = 0; n < 512; ++n) {
        float px = gp[3 * n + 0], py = gp[3 * n + 1], pz = gp[3 * n + 2];
        float sp = __fadd_rn(__fadd_rn(__fmul_rn(px, px), __fmul_rn(py, py)),
                             __fmul_rn(pz, pz));
        float e  = fmaf(vz, pz, fmaf(vy, py, __fmul_rn(vx, px)));
        float d2 = __fadd_rn(__fsub_rn(sv, __fmul_rn(2.0f, e)), sp);
        if (d2 < best) { best = d2; bi = n; }
    }
    bi += chunk * 512;
    __shared__ float sd[256];
    __shared__ int   si[256];
    sd[t] = best;
    si[t] = bi;
    __syncthreads();
    if (t < 64) {
        #pragma unroll
        for (int c = 1; c < 4; ++c) {
            float d = sd[c * 64 + lane];
            int   i = si[c * 64 + lane];
            if (d < best) { best = d; bi = i; }
        }
        out[(size_t)b * VV + v] = mlp_out[b * NN + bi];
    }
}

extern "C" void kernel_launch(void* const* d_in, const int* in_sizes, int n_in,
                              void* d_out, int out_size, void* d_ws, size_t ws_size,
                              hipStream_t stream) {
    const float* verts     = (const float*)d_in[0];
    const float* graph_pos = (const float*)d_in[1];
    const float* processed = (const float*)d_in[2];
    const float* W1        = (const float*)d_in[3];
    const float* b1        = (const float*)d_in[4];
    const float* W2        = (const float*)d_in[5];
    const float* b2        = (const float*)d_in[6];
    float* out     = (float*)d_out;
    float* mlp_out = (float*)d_ws;                               // 64 KB
    float4* qpt    = (float4*)((char*)d_ws + BB * NN * 4);       // 256 KB

    const size_t need = (size_t)BB * NN * 4 + (size_t)BB * NN * 16;
    if (ws_size >= need) {
        hipLaunchKernelGGL(mlp_qpt_kernel, dim3(528), dim3(256), 0, stream,
                           processed, W1, b1, W2, b2, graph_pos, mlp_out, qpt);
        hipLaunchKernelGGL(argmin_gather_lds_kernel, dim3(BB * (VV / 128)), dim3(512), 0, stream,
                           verts, qpt, mlp_out, out);
    } else {
        hipLaunchKernelGGL(mlp_rows_kernel, dim3((BB * NN) / 64), dim3(256), 0, stream,
                           processed, W1, b1, W2, b2, mlp_out);
        hipLaunchKernelGGL(argmin_gather_kernel, dim3(BB * (VV / 64)), dim3(256), 0, stream,
                           verts, graph_pos, mlp_out, out);
    }
}

// Round 7
// 108.518 us; speedup vs baseline: 1.2288x; 1.0174x over previous
//
#include <hip/hip_runtime.h>

// Problem constants (B=8, V=8192, N=2048, C=128)
#define BB 8
#define VV 8192
#define NN 2048
#define CC 128

#define MLP_LD 36     // 128 x 36 f32 selT tile: 16B-aligned rows, conflict-free b128 reads

// ---------------------------------------------------------------------------
// Kernel 1: MLP over B*N rows (32 rows/block, 4x4 micro-tile, 512 blocks).
// mlp_out[row] = relu(processed[row,:] @ W1 + b1) @ W2 + b2
// ---------------------------------------------------------------------------
__global__ __launch_bounds__(256) void mlp_kernel(
    const float* __restrict__ processed, const float* __restrict__ W1,
    const float* __restrict__ b1, const float* __restrict__ W2,
    const float* __restrict__ b2, float* __restrict__ mlp_out)
{
    __shared__ float selT[CC * MLP_LD];   // selT[k][r], r in [0,32)
    const int t = threadIdx.x;
    const int row0 = blockIdx.x * 32;

    #pragma unroll
    for (int i = 0; i < 16; ++i) {
        int flat = i * 256 + t;           // 0..4095
        int r = flat >> 7;                // 0..31
        int k = flat & 127;
        selT[k * MLP_LD + r] = processed[(size_t)(row0 + r) * CC + k];
    }
    __syncthreads();

    const int g = t & 31;                 // col group: 4 cols each
    const int rblk = t >> 5;              // row group: 4 rows each
    const int c0 = g * 4;
    const int r0 = rblk * 4;

    float acc[4][4];
    #pragma unroll
    for (int i = 0; i < 4; ++i)
        #pragma unroll
        for (int j = 0; j < 4; ++j) acc[i][j] = 0.f;

    #pragma unroll 4
    for (int k = 0; k < CC; ++k) {
        float4 wv = *(const float4*)(W1 + k * CC + c0);
        float4 av4 = *(const float4*)(&selT[k * MLP_LD + r0]);
        float av[4] = {av4.x, av4.y, av4.z, av4.w};
        #pragma unroll
        for (int i = 0; i < 4; ++i) {
            acc[i][0] = fmaf(av[i], wv.x, acc[i][0]);
            acc[i][1] = fmaf(av[i], wv.y, acc[i][1]);
            acc[i][2] = fmaf(av[i], wv.z, acc[i][2]);
            acc[i][3] = fmaf(av[i], wv.w, acc[i][3]);
        }
    }

    float4 b1v = *(const float4*)(b1 + c0);
    float4 w2v = *(const float4*)(W2 + c0);
    float bias2 = b2[0];

    #pragma unroll
    for (int i = 0; i < 4; ++i) {
        float h0 = acc[i][0] + b1v.x; h0 = h0 > 0.f ? h0 : 0.f;
        float h1 = acc[i][1] + b1v.y; h1 = h1 > 0.f ? h1 : 0.f;
        float h2 = acc[i][2] + b1v.z; h2 = h2 > 0.f ? h2 : 0.f;
        float h3 = acc[i][3] + b1v.w; h3 = h3 > 0.f ? h3 : 0.f;
        float p = fmaf(h0, w2v.x, fmaf(h1, w2v.y, fmaf(h2, w2v.z, h3 * w2v.w)));
        // reduce across the 32 col-lanes (xor offsets <32 stay in each half-wave)
        #pragma unroll
        for (int off = 1; off < 32; off <<= 1) p += __shfl_xor(p, off, 64);
        if (g == 0) mlp_out[row0 + r0 + i] = p + bias2;
    }
}

// ---------------------------------------------------------------------------
// Kernel 2: argmin + gather, Vt=4 vertices/lane (1 ds_read_b128 feeds 32 VALU
// -> VALU-bound, not LDS-pipe-bound). Block = 1024 thr = 16 waves; block
// covers 256 vertices; wave w scans point chunk [w*128, (w+1)*128).
// Staging computes sp in-kernel with the EXACT reference rounding:
//   sp = (rn(px^2)+rn(py^2))+rn(pz^2)
// Bit-exact d2: e2 = fma(2vz,pz, fma(2vy,py, rn(2vx*px))) == rn(2e);
//              d2 = rn(rn(sv - e2) + sp).
// Strict < + ascending chunk merge preserves first-index tie-break.
// ---------------------------------------------------------------------------
__global__ __launch_bounds__(1024) void argmin_gather_v4_kernel(
    const float* __restrict__ verts, const float* __restrict__ graph_pos,
    const float* __restrict__ mlp_out, float* __restrict__ out)
{
    __shared__ float4 pts[NN];              // 32 KB
    __shared__ float  sd[16 * 256];         // 16 KB
    __shared__ unsigned short si[16 * 256]; //  8 KB

    const int bid = blockIdx.x;             // 256 blocks
    const int b  = bid >> 5;                // 32 blocks per batch
    const int v0 = (bid & 31) * 256;
    const int t = threadIdx.x;
    const int lane = t & 63;
    const int w = __builtin_amdgcn_readfirstlane(t >> 6);   // wave id = chunk id, 0..15

    // stage all 2048 points of batch b, computing sp exactly
    #pragma unroll
    for (int i = 0; i < 2; ++i) {
        int p = t + i * 1024;
        const float* g3 = graph_pos + ((size_t)b * NN + p) * 3;
        float px = g3[0], py = g3[1], pz = g3[2];
        float sp = __fadd_rn(__fadd_rn(__fmul_rn(px, px), __fmul_rn(py, py)),
                             __fmul_rn(pz, pz));
        pts[p] = make_float4(px, py, pz, sp);
    }

    // four vertices per lane
    float sv[4], tx[4], ty[4], tz[4];
    #pragma unroll
    for (int j = 0; j < 4; ++j) {
        int v = v0 + j * 64 + lane;
        const float* vp = verts + ((size_t)b * VV + v) * 3;
        float x = vp[0], y = vp[1], z = vp[2];
        sv[j] = __fadd_rn(__fadd_rn(__fmul_rn(x, x), __fmul_rn(y, y)),
                          __fmul_rn(z, z));
        tx[j] = x + x; ty[j] = y + y; tz[j] = z + z;   // exact 2x
    }
    __syncthreads();

    const float4* P = &pts[w * 128];
    float best[4] = {3.4e38f, 3.4e38f, 3.4e38f, 3.4e38f};
    int bi[4] = {0, 0, 0, 0};
    #pragma unroll 4
    for (int n = 0; n < 128; ++n) {
        float4 Q = P[n];   // ds_read_b128, same-addr broadcast (conflict-free)
        #pragma unroll
        for (int j = 0; j < 4; ++j) {
            float e2 = fmaf(tz[j], Q.z, fmaf(ty[j], Q.y, __fmul_rn(tx[j], Q.x)));
            float d2 = __fadd_rn(__fsub_rn(sv[j], e2), Q.w);
            if (d2 < best[j]) { best[j] = d2; bi[j] = n; }  // strict <: first index
        }
    }

    #pragma unroll
    for (int j = 0; j < 4; ++j) {
        sd[w * 256 + j * 64 + lane] = best[j];
        si[w * 256 + j * 64 + lane] = (unsigned short)(bi[j] + w * 128);
    }
    __syncthreads();

    if (t < 256) {
        float bb = sd[t];
        int   ii = si[t];
        #pragma unroll
        for (int c = 1; c < 16; ++c) {      // ascending chunks: first-index ties
            float d = sd[c * 256 + t];
            int   i = si[c * 256 + t];
            if (d < bb) { bb = d; ii = i; }
        }
        out[(size_t)b * VV + v0 + t] = mlp_out[b * NN + ii];
    }
}

extern "C" void kernel_launch(void* const* d_in, const int* in_sizes, int n_in,
                              void* d_out, int out_size, void* d_ws, size_t ws_size,
                              hipStream_t stream) {
    const float* verts     = (const float*)d_in[0];
    const float* graph_pos = (const float*)d_in[1];
    const float* processed = (const float*)d_in[2];
    const float* W1        = (const float*)d_in[3];
    const float* b1        = (const float*)d_in[4];
    const float* W2        = (const float*)d_in[5];
    const float* b2        = (const float*)d_in[6];
    float* out     = (float*)d_out;
    float* mlp_out = (float*)d_ws;     // 16384 floats = 64 KB scratch

    hipLaunchKernelGGL(mlp_kernel, dim3((BB * NN) / 32), dim3(256), 0, stream,
                       processed, W1, b1, W2, b2, mlp_out);
    hipLaunchKernelGGL(argmin_gather_v4_kernel, dim3(BB * (VV / 256)), dim3(1024), 0, stream,
                       verts, graph_pos, mlp_out, out);
}